// Round 9
// baseline (90.239 us; speedup 1.0000x reference)
//
#include <hip/hip_runtime.h>
#include <hip/hip_bf16.h>
#include <cstdint>

#define HIDDEN 384
#define NSUPER 2048
#define MAXDEG 32
#define FRAGS (12*24*64)            // fragments*lanes per 384x384 block
#define WBLK  (FRAGS*8)             // shorts per repacked 384x384 block = 147456

typedef __attribute__((ext_vector_type(8))) short bf16x8;
typedef __attribute__((ext_vector_type(4))) float f32x4;

__device__ inline unsigned short f2bf(float f) {
    __hip_bfloat16 h = __float2bfloat16(f);   // RNE
    return *reinterpret_cast<unsigned short*>(&h);
}
__device__ inline float b2f(unsigned short s) {
    return __uint_as_float(((unsigned int)s) << 16);
}
__device__ inline bf16x8 pack8(const float* v) {
    union { bf16x8 v8; unsigned short u[8]; } u;
    #pragma unroll
    for (int i = 0; i < 8; ++i) u.u[i] = f2bf(v[i]);
    return u.v8;
}
// Abramowitz-Stegun 7.1.26: |err| <= 1.5e-7, branchless
__device__ inline float fast_erf(float x) {
    float ax = fabsf(x);
    float t  = 1.0f / fmaf(0.3275911f, ax, 1.0f);
    float p  = t*(0.254829592f + t*(-0.284496736f + t*(1.421413741f +
               t*(-1.453152027f + t*1.061405429f))));
    float e  = __expf(-ax*ax);
    return copysignf(1.0f - p*e, x);
}
__device__ inline float gelu(float y) {
    return 0.5f * y * (1.0f + fast_erf(y * 0.70710678118654752f));
}

// ---- K1: weight repacks + mask detect + supernode embeds, ONE launch ----
__global__ __launch_bounds__(256)
void prep(const float* __restrict__ W1, const float* __restrict__ W2,
          const float* __restrict__ Wp, const unsigned int* __restrict__ mask,
          const float* __restrict__ pos, const float* __restrict__ feat,
          const int* __restrict__ sn_idx,
          const float* __restrict__ W_in, const float* __restrict__ b_in,
          unsigned short* __restrict__ w1sf, unsigned short* __restrict__ w1df,
          unsigned short* __restrict__ w2f,  unsigned short* __restrict__ wpf,
          unsigned short* __restrict__ snxb, int* __restrict__ flag) {
    const int b = blockIdx.x;
    const int t = threadIdx.x;
    if (b == 360) {   // mask detect: uint8 numpy-bool vs int32
        __shared__ int s;
        if (t == 0) s = 0;
        __syncthreads();
        int bad = 0;
        for (int i = t; i < 16384; i += 256)
            if (mask[i] > 1u) bad = 1;
        if (bad) s = 1;
        __syncthreads();
        if (t == 0) *flag = s;   // 1 => uint8, 0 => int32
        return;
    }
    if (b > 360) {    // ---- supernode embeds ----
        __shared__ float W4[HIDDEN][4];
        __shared__ float P6[64][7];
        const int eb = b - 361;   // 0..31
        if (t < 64) {
            const int pi = sn_idx[eb*64 + t];
            P6[t][0]=pos[pi*3];  P6[t][1]=pos[pi*3+1];  P6[t][2]=pos[pi*3+2];
            P6[t][3]=feat[pi*3]; P6[t][4]=feat[pi*3+1]; P6[t][5]=feat[pi*3+2];
        }
        for (int d = t; d < HIDDEN; d += 256) {
            W4[d][0]=W_in[d]; W4[d][1]=W_in[HIDDEN+d];
            W4[d][2]=W_in[2*HIDDEN+d]; W4[d][3]=b_in[d];
        }
        __syncthreads();
        const int er = t >> 2, seg = t & 3;
        float frA[8], frB[8];
        #pragma unroll
        for (int i = 0; i < 8; ++i) {
            frA[i] = exp2f(-(float)(seg*8 + i)      * 0.2076205059304601f);
            frB[i] = exp2f(-(float)(32 + seg*8 + i) * 0.2076205059304601f);
        }
        const float f0 = P6[er][3], f1 = P6[er][4], f2 = P6[er][5];
        #pragma unroll
        for (int cc = 0; cc < 3; ++cc) {
            const float pc = P6[er][cc];
            float sL[8], sH[8], cL[8], cH[8];
            #pragma unroll
            for (int i = 0; i < 8; ++i) {
                const float aL = pc*frA[i], aH = pc*frB[i];
                sL[i]=__sinf(aL); sH[i]=__sinf(aH); cL[i]=__cosf(aL); cH[i]=__cosf(aH);
            }
            #pragma unroll
            for (int q = 0; q < 4; ++q) {
                const float* bb = (q==0)?sL:(q==1)?sH:(q==2)?cL:cH;
                const int blk = cc*4 + q;
                float v[8];
                #pragma unroll
                for (int i = 0; i < 8; ++i) {
                    const int dim = blk*32 + seg*8 + i;
                    const float4 wv = *(const float4*)W4[dim];
                    v[i] = fmaf(f0, wv.x, fmaf(f1, wv.y, fmaf(f2, wv.z, bb[i] + wv.w)));
                }
                *(bf16x8*)&snxb[(size_t)(eb*64 + er)*HIDDEN + blk*32 + seg*8] = pack8(v);
            }
        }
        return;
    }
    // ---- repack: frag (kt,nt): lane l elem j = W[kt*32+(l>>4)*8+j][nt*16+(l&15)]
    const int grp = b / 72, sub = b % 72;
    const float* W; unsigned short* out;
    switch (grp) {
        case 0: W = W1;              out = w1sf; break;
        case 1: W = W1 + 384*HIDDEN; out = w1df; break;
        case 2: W = W2;              out = w2f;  break;
        case 3: W = Wp;              out = wpf;  break;
        default:W = Wp + 384*HIDDEN; out = wpf + WBLK; break;
    }
    const int idx = sub * 256 + t;   // 72*256 == FRAGS exactly
    const int l   = idx & 63;
    const int frag= idx >> 6;
    const int nt  = frag % 24;
    const int kt  = frag / 24;
    const int col = nt * 16 + (l & 15);
    const int k0  = kt * 32 + (l >> 4) * 8;
    unsigned int pk[4];
    #pragma unroll
    for (int j = 0; j < 4; ++j) {
        unsigned int lo = f2bf(W[(k0 + 2*j)     * HIDDEN + col]);
        unsigned int hi = f2bf(W[(k0 + 2*j + 1) * HIDDEN + col]);
        pk[j] = lo | (hi << 16);
    }
    *reinterpret_cast<uint4*>(&out[(size_t)idx * 8]) =
        *reinterpret_cast<const uint4*>(pk);
}

// ---- K2: dstv[2048][384] = snxb @ W1dst + b1.  128 blocks = 32 rg x 4 cq ----
__global__ __launch_bounds__(256)
void k_dstv(const unsigned short* __restrict__ snxb,
            const unsigned short* __restrict__ w1df,
            const float* __restrict__ b1, float* __restrict__ dstv) {
    const int rg = blockIdx.x >> 2, cq = blockIdx.x & 3;
    const int t = threadIdx.x, w = t>>6, l = t&63, lg = l>>4, l15 = l&15;
    const int wgm = w>>1, wgn = w&1;
    const int r0 = rg*64 + wgm*32;
    const int ntb = cq*6 + wgn*3;
    f32x4 acc[2][3];
    #pragma unroll
    for (int mt=0; mt<2; ++mt)
        #pragma unroll
        for (int nt=0; nt<3; ++nt) acc[mt][nt] = (f32x4){0.f,0.f,0.f,0.f};
    #pragma unroll 2
    for (int kt = 0; kt < 12; ++kt) {
        bf16x8 a[2], bfr[3];
        const unsigned short* bpp = &w1df[((size_t)(kt*24 + ntb)*64 + l)*8];
        #pragma unroll
        for (int nt=0; nt<3; ++nt) bfr[nt] = *(const bf16x8*)(bpp + (size_t)nt*512);
        #pragma unroll
        for (int mt=0; mt<2; ++mt)
            a[mt] = *(const bf16x8*)&snxb[(size_t)(r0 + mt*16 + l15)*HIDDEN + kt*32 + lg*8];
        #pragma unroll
        for (int mt=0; mt<2; ++mt)
            #pragma unroll
            for (int nt=0; nt<3; ++nt)
                acc[mt][nt] = __builtin_amdgcn_mfma_f32_16x16x32_bf16(a[mt], bfr[nt], acc[mt][nt], 0,0,0);
    }
    #pragma unroll
    for (int mt=0; mt<2; ++mt)
        #pragma unroll
        for (int nt=0; nt<3; ++nt) {
            const int col = cq*96 + wgn*48 + nt*16 + l15;
            #pragma unroll
            for (int r=0; r<4; ++r) {
                const int row = r0 + mt*16 + lg*4 + r;
                dstv[(size_t)row*HIDDEN + col] = acc[mt][nt][r] + b1[col];
            }
        }
}

// ---- K3: fused edge MLP, CONVOY-BROKEN layer 1 ----
// 256 thr (4 waves), 64 edges (2 sn)/block, grid 1024. Layer-1 interleaves
// {AREAD(kt), LOADB(kt+1), EMB(kt+1)->G, MFMA(kt)} per K-tile so VALU and
// MFMA pipes run concurrently instead of phase-locked convoys (r8: 24.6%
// Mfma + 54% VALU with neither overlapped). G doubles as progressive buffer:
// tile kt+1 slots are disjoint from tile kt, one barrier per kt.
__global__ __launch_bounds__(256, 2)
void k_mlp(const float* __restrict__ pos, const float* __restrict__ feat,
           const int* __restrict__ nbr_idx, const void* __restrict__ mask_raw,
           const int* __restrict__ mask_fmt,
           const float* __restrict__ W_in, const float* __restrict__ b_in,
           const float* __restrict__ dstv,
           const unsigned short* __restrict__ W1f,
           const unsigned short* __restrict__ W2f,
           const float* __restrict__ b2, unsigned short* __restrict__ aggb)
{
    __shared__ unsigned short G[4*12*64*8];   // 49152 B frag-major
    __shared__ ushort4 WINTB[HIDDEN];         // 3072 B bf16 {w0,w1,w2,b}
    __shared__ float PF[64][7];               // 1792 B pos3,feat3,mval
    __shared__ float CNT[2];

    const int t  = threadIdx.x;
    const int bm = blockIdx.x;
    const int l = t & 63, ng = t >> 6, lg = l >> 4, l15 = l & 15;

    // early: dstv slice into regs (used only at gelu; latency hides under prologue)
    float dvreg[2][6];
    #pragma unroll
    for (int sl = 0; sl < 2; ++sl)
        #pragma unroll
        for (int nt = 0; nt < 6; ++nt)
            dvreg[sl][nt] = dstv[(size_t)(bm*2 + sl)*HIDDEN + ng*96 + nt*16 + l15];

    bf16x8 bA[6], bB[6];
    #define LOADB(dst, Wf, kt)                                                  \
        { const unsigned short* bp_ = &Wf[((size_t)((kt)*24 + ng*6)*64 + l)*8]; \
          _Pragma("unroll")                                                     \
          for (int nt_ = 0; nt_ < 6; ++nt_)                                     \
              dst[nt_] = *(const bf16x8*)(bp_ + (size_t)nt_*512); }
    #define AREAD(a_, kt)                                                       \
        { _Pragma("unroll")                                                     \
          for (int mt_ = 0; mt_ < 4; ++mt_)                                     \
              a_[mt_] = *(const bf16x8*)&G[(size_t)(((mt_*12 + (kt))*64) + l)*8]; }
    #define MFMA6(bfr, a_)                                                      \
        { __builtin_amdgcn_s_setprio(1);                                        \
          _Pragma("unroll")                                                     \
          for (int mt_ = 0; mt_ < 4; ++mt_)                                     \
              _Pragma("unroll")                                                 \
              for (int nt_ = 0; nt_ < 6; ++nt_)                                 \
                  acc[mt_][nt_] = __builtin_amdgcn_mfma_f32_16x16x32_bf16(      \
                      a_[mt_], bfr[nt_], acc[mt_][nt_], 0, 0, 0);               \
          __builtin_amdgcn_s_setprio(0); }

    // hoist layer-1 kt=0 weight load: lands during prologue/embed(0)
    LOADB(bA, W1f, 0);

    if (t < 64) {
        const int e  = bm*64 + t;
        const int pi = nbr_idx[e];
        PF[t][0]=pos[pi*3];  PF[t][1]=pos[pi*3+1];  PF[t][2]=pos[pi*3+2];
        PF[t][3]=feat[pi*3]; PF[t][4]=feat[pi*3+1]; PF[t][5]=feat[pi*3+2];
        const int fmt = *mask_fmt;
        const int mv  = fmt ? (int)((const unsigned char*)mask_raw)[e]
                            : ((const int*)mask_raw)[e];
        PF[t][6] = mv ? 1.0f : 0.0f;
    }
    for (int d = t; d < HIDDEN; d += 256) {
        ushort4 wv;
        wv.x = f2bf(W_in[d]); wv.y = f2bf(W_in[HIDDEN+d]);
        wv.z = f2bf(W_in[2*HIDDEN+d]); wv.w = f2bf(b_in[d]);
        WINTB[d] = wv;
    }
    __syncthreads();
    if (t < 2) {
        float c = 0.f;
        for (int s = 0; s < 32; ++s) c += PF[t*32+s][6];
        CNT[t] = c;   // read after later barriers
    }

    // ---- per-thread embed state (row er, 8-dim group seg within each 32) ----
    const int er = t >> 2, seg = t & 3;
    float frA[8], frB[8];
    #pragma unroll
    for (int i = 0; i < 8; ++i) {
        frA[i] = exp2f(-(float)(seg*8 + i)      * 0.2076205059304601f);
        frB[i] = exp2f(-(float)(32 + seg*8 + i) * 0.2076205059304601f);
    }
    const float f0 = PF[er][3], f1 = PF[er][4], f2 = PF[er][5];
    const float pc0 = PF[er][0], pc1 = PF[er][1], pc2 = PF[er][2];
    const int slotbase = (er>>4)*12*64 + seg*16 + (er&15);

    // EMB(kt): fill G tile kt (64 rows x dims [kt*32, kt*32+32)). kt is a
    // compile-time constant at every use (unrolled) => all selects static.
    #define EMB(kt_)                                                            \
        { const float pc = ((kt_)>>2)==0 ? pc0 : (((kt_)>>2)==1 ? pc1 : pc2);   \
          float v[8];                                                           \
          _Pragma("unroll")                                                     \
          for (int i = 0; i < 8; ++i) {                                         \
              const float fr = ((kt_)&1) ? frB[i] : frA[i];                     \
              const float aa = pc * fr;                                         \
              const float base = (((kt_)>>1)&1) ? __cosf(aa) : __sinf(aa);      \
              const ushort4 wv = WINTB[(kt_)*32 + seg*8 + i];                   \
              v[i] = fmaf(f0, b2f(wv.x), fmaf(f1, b2f(wv.y),                    \
                     fmaf(f2, b2f(wv.z), base + b2f(wv.w))));                   \
          }                                                                     \
          *(bf16x8*)&G[(size_t)(slotbase + (kt_)*64)*8] = pack8(v); }

    EMB(0);
    __syncthreads();   // tile 0 ready

    f32x4 acc[4][6];
    #pragma unroll
    for (int mt=0; mt<4; ++mt)
        #pragma unroll
        for (int nt=0; nt<6; ++nt) acc[mt][nt] = (f32x4){0.f,0.f,0.f,0.f};

    // ---- layer 1: interleaved {AREAD | LOADB next | EMB next | MFMA} ----
    #pragma unroll
    for (int kt = 0; kt < 12; kt += 2) {
        bf16x8 a[4];
        AREAD(a, kt);
        LOADB(bB, W1f, kt + 1);
        EMB(kt + 1);
        MFMA6(bA, a);
        __syncthreads();                 // tile kt+1 visible
        AREAD(a, kt + 1);
        if (kt + 2 < 12) { LOADB(bA, W1f, kt + 2); EMB(kt + 2); }
        MFMA6(bB, a);
        __syncthreads();                 // tile kt+2 visible / pre-gelu fence
    }

    // ---- gelu epilogue: scatter bf16 into frag-major G for layer 2 ----
    #pragma unroll
    for (int mt=0; mt<4; ++mt) {
        const int sl = mt >> 1;   // supernode slot (rows 0..31 vs 32..63)
        #pragma unroll
        for (int nt=0; nt<6; ++nt) {
            const int col = ng*96 + nt*16 + l15;
            const float dv = dvreg[sl][nt];
            const int base = ((mt*12 + (col>>5))*64 + ((col>>3)&3)*16 + lg*4)*8 + (col&7);
            #pragma unroll
            for (int r=0; r<4; ++r)
                G[base + r*8] = f2bf(gelu(acc[mt][nt][r] + dv));
        }
    }
    __syncthreads();

    // ---- layer 2: Y2 = G @ W2 (pure GEMM, B 2-deep prefetch) ----
    #pragma unroll
    for (int mt=0; mt<4; ++mt)
        #pragma unroll
        for (int nt=0; nt<6; ++nt) acc[mt][nt] = (f32x4){0.f,0.f,0.f,0.f};
    LOADB(bA, W2f, 0); LOADB(bB, W2f, 1);
    #pragma unroll
    for (int kt = 0; kt < 12; kt += 2) {
        bf16x8 a[4];
        AREAD(a, kt);
        MFMA6(bA, a);
        if (kt + 2 < 12) LOADB(bA, W2f, kt + 2);
        AREAD(a, kt + 1);
        MFMA6(bB, a);
        if (kt + 3 < 12) LOADB(bB, W2f, kt + 3);
    }

    // ---- masked mean -> aggb (bf16, b2 folded) ----
    #pragma unroll
    for (int nt=0; nt<6; ++nt) {
        const int col = ng*96 + nt*16 + l15;
        float s0 = 0.f, s1 = 0.f;
        #pragma unroll
        for (int mt=0; mt<4; ++mt) {
            float p = 0.f;
            #pragma unroll
            for (int r=0; r<4; ++r)
                p += PF[mt*16 + lg*4 + r][6] * acc[mt][nt][r];
            if (mt < 2) s0 += p; else s1 += p;
        }
        s0 += __shfl_xor(s0,16); s0 += __shfl_xor(s0,32);
        s1 += __shfl_xor(s1,16); s1 += __shfl_xor(s1,32);
        if (lg == 0) {
            const float bb = b2[col];
            const int sn0 = bm*2;
            const float c0 = CNT[0], c1 = CNT[1];
            aggb[(size_t)sn0*HIDDEN + col]     = f2bf(s0 / fmaxf(c0,1.f) + bb*(c0>0.f?1.f:0.f));
            aggb[(size_t)(sn0+1)*HIDDEN + col] = f2bf(s1 / fmaxf(c1,1.f) + bb*(c1>0.f?1.f:0.f));
        }
    }
    #undef LOADB
    #undef AREAD
    #undef MFMA6
    #undef EMB
}

// ---- K4: projection out = [aggb|snxb] @ Wp + bp. 128 blocks = 32 rg x 4 cq ----
__global__ __launch_bounds__(256)
void k_proj(const unsigned short* __restrict__ aggb,
            const unsigned short* __restrict__ snxb,
            const unsigned short* __restrict__ wpf,
            const float* __restrict__ bp, float* __restrict__ out) {
    const int rg = blockIdx.x >> 2, cq = blockIdx.x & 3;
    const int t = threadIdx.x, w = t>>6, l = t&63, lg = l>>4, l15 = l&15;
    const int wgm = w>>1, wgn = w&1;
    const int r0 = rg*64 + wgm*32;
    const int ntb = cq*6 + wgn*3;
    f32x4 acc[2][3];
    #pragma unroll
    for (int mt=0; mt<2; ++mt)
        #pragma unroll
        for (int nt=0; nt<3; ++nt) acc[mt][nt] = (f32x4){0.f,0.f,0.f,0.f};
    #pragma unroll 2
    for (int kt = 0; kt < 24; ++kt) {
        const unsigned short* Ab = (kt < 12) ? aggb : snxb;
        const unsigned short* Wb = (kt < 12) ? wpf  : wpf + WBLK;
        const int ktt = (kt < 12) ? kt : kt - 12;
        bf16x8 a[2], bfr[3];
        const unsigned short* bpp = &Wb[((size_t)(ktt*24 + ntb)*64 + l)*8];
        #pragma unroll
        for (int nt=0; nt<3; ++nt) bfr[nt] = *(const bf16x8*)(bpp + (size_t)nt*512);
        #pragma unroll
        for (int mt=0; mt<2; ++mt)
            a[mt] = *(const bf16x8*)&Ab[(size_t)(r0 + mt*16 + l15)*HIDDEN + ktt*32 + lg*8];
        #pragma unroll
        for (int mt=0; mt<2; ++mt)
            #pragma unroll
            for (int nt=0; nt<3; ++nt)
                acc[mt][nt] = __builtin_amdgcn_mfma_f32_16x16x32_bf16(a[mt], bfr[nt], acc[mt][nt], 0,0,0);
    }
    #pragma unroll
    for (int mt=0; mt<2; ++mt)
        #pragma unroll
        for (int nt=0; nt<3; ++nt) {
            const int col = cq*96 + wgn*48 + nt*16 + l15;
            #pragma unroll
            for (int r=0; r<4; ++r) {
                const int row = r0 + mt*16 + lg*4 + r;
                out[(size_t)row*HIDDEN + col] = acc[mt][nt][r] + bp[col];
            }
        }
}

extern "C" void kernel_launch(void* const* d_in, const int* in_sizes, int n_in,
                              void* d_out, int out_size, void* d_ws, size_t ws_size,
                              hipStream_t stream) {
    const float* pos   = (const float*)d_in[0];
    const float* feat  = (const float*)d_in[1];
    const int*   sn    = (const int*)d_in[2];
    const int*   nbr   = (const int*)d_in[3];
    const void*  mask  = d_in[4];
    const float* W_in  = (const float*)d_in[5];
    const float* b_in  = (const float*)d_in[6];
    const float* W1    = (const float*)d_in[7];
    const float* b1    = (const float*)d_in[8];
    const float* W2    = (const float*)d_in[9];
    const float* b2    = (const float*)d_in[10];
    const float* Wp    = (const float*)d_in[11];
    const float* bpv   = (const float*)d_in[12];
    float* out = (float*)d_out;

    char* base = (char*)d_ws;
    int* flag = (int*)base;
    unsigned short* w1sf = (unsigned short*)(base + 256);
    unsigned short* w1df = w1sf + WBLK;
    unsigned short* w2f  = w1df + WBLK;
    unsigned short* wpf  = w2f  + WBLK;                  // 2 blocks (768 rows)
    unsigned short* snxb = wpf  + 2*(size_t)WBLK;        // 2048*384 bf16
    unsigned short* aggb = snxb + (size_t)NSUPER*HIDDEN;
    float* dstv = (float*)(aggb + (size_t)NSUPER*HIDDEN); // 2048*384 f32

    hipLaunchKernelGGL(prep, dim3(393), dim3(256), 0, stream,
                       W1, W2, Wp, (const unsigned int*)mask,
                       pos, feat, sn, W_in, b_in,
                       w1sf, w1df, w2f, wpf, snxb, flag);
    hipLaunchKernelGGL(k_dstv, dim3(128), dim3(256), 0, stream,
                       snxb, w1df, b1, dstv);
    hipLaunchKernelGGL(k_mlp, dim3(1024), dim3(256), 0, stream,
                       pos, feat, nbr, mask, flag, W_in, b_in, dstv, w1sf, w2f, b2, aggb);
    hipLaunchKernelGGL(k_proj, dim3(128), dim3(256), 0, stream,
                       aggb, snxb, wpf, bpv, out);
}

// Round 10
// 84.443 us; speedup vs baseline: 1.0686x; 1.0686x over previous
//
#include <hip/hip_runtime.h>
#include <hip/hip_bf16.h>
#include <cstdint>

#define HIDDEN 384
#define NSUPER 2048
#define MAXDEG 32
#define FRAGS (12*24*64)            // fragments*lanes per 384x384 block
#define WBLK  (FRAGS*8)             // shorts per repacked 384x384 block = 147456

typedef __attribute__((ext_vector_type(8))) short bf16x8;
typedef __attribute__((ext_vector_type(4))) float f32x4;

// branchless RNE f32->bf16 (no NaN path; all values here are finite).
// __float2bfloat16 compiles to a branchy NaN-checking sequence (~10 instr);
// this is 4 VALU ops and bit-identical for finite inputs.
__device__ inline unsigned short f2bf(float f) {
    unsigned int u = __float_as_uint(f);
    return (unsigned short)((u + 0x7fffu + ((u >> 16) & 1u)) >> 16);
}
__device__ inline float b2f(unsigned short s) {
    return __uint_as_float(((unsigned int)s) << 16);
}
__device__ inline bf16x8 pack8(const float* v) {
    union { bf16x8 v8; unsigned short u[8]; } u;
    #pragma unroll
    for (int i = 0; i < 8; ++i) u.u[i] = f2bf(v[i]);
    return u.v8;
}
// tanh-form gelu as y*sigmoid(2u): ~9 VALU ops, |err vs exact| <= ~1e-3
// (propagates <= ~4e-4 to final output through W2/Wp; budget 1.67e-2).
__device__ inline float gelu(float y) {
    const float y2 = y * y;
    const float m  = __expf(y * fmaf(-0.0713548163f, y2, -1.5957691216f));
    return y * (1.0f / (1.0f + m));
}

// ---- K1: weight repacks + mask detect + supernode embeds, ONE launch ----
__global__ __launch_bounds__(256)
void prep(const float* __restrict__ W1, const float* __restrict__ W2,
          const float* __restrict__ Wp, const unsigned int* __restrict__ mask,
          const float* __restrict__ pos, const float* __restrict__ feat,
          const int* __restrict__ sn_idx,
          const float* __restrict__ W_in, const float* __restrict__ b_in,
          unsigned short* __restrict__ w1sf, unsigned short* __restrict__ w1df,
          unsigned short* __restrict__ w2f,  unsigned short* __restrict__ wpf,
          unsigned short* __restrict__ snxb, int* __restrict__ flag) {
    const int b = blockIdx.x;
    const int t = threadIdx.x;
    if (b == 360) {   // mask detect: uint8 numpy-bool vs int32
        __shared__ int s;
        if (t == 0) s = 0;
        __syncthreads();
        int bad = 0;
        for (int i = t; i < 16384; i += 256)
            if (mask[i] > 1u) bad = 1;
        if (bad) s = 1;
        __syncthreads();
        if (t == 0) *flag = s;   // 1 => uint8, 0 => int32
        return;
    }
    if (b > 360) {    // ---- supernode embeds -> snxb ----
        __shared__ float W4[HIDDEN][4];
        __shared__ float P6[64][7];
        const int eb = b - 361;   // 0..31
        if (t < 64) {
            const int pi = sn_idx[eb*64 + t];
            P6[t][0]=pos[pi*3];  P6[t][1]=pos[pi*3+1];  P6[t][2]=pos[pi*3+2];
            P6[t][3]=feat[pi*3]; P6[t][4]=feat[pi*3+1]; P6[t][5]=feat[pi*3+2];
        }
        for (int d = t; d < HIDDEN; d += 256) {
            W4[d][0]=W_in[d]; W4[d][1]=W_in[HIDDEN+d];
            W4[d][2]=W_in[2*HIDDEN+d]; W4[d][3]=b_in[d];
        }
        __syncthreads();
        const int er = t >> 2, seg = t & 3;
        float frA[8], frB[8];
        #pragma unroll
        for (int i = 0; i < 8; ++i) {
            frA[i] = exp2f(-(float)(seg*8 + i)      * 0.2076205059304601f);
            frB[i] = exp2f(-(float)(32 + seg*8 + i) * 0.2076205059304601f);
        }
        const float f0 = P6[er][3], f1 = P6[er][4], f2 = P6[er][5];
        #pragma unroll
        for (int cc = 0; cc < 3; ++cc) {
            const float pc = P6[er][cc];
            float sL[8], sH[8], cL[8], cH[8];
            #pragma unroll
            for (int i = 0; i < 8; ++i) {
                const float aL = pc*frA[i], aH = pc*frB[i];
                sL[i]=__sinf(aL); sH[i]=__sinf(aH); cL[i]=__cosf(aL); cH[i]=__cosf(aH);
            }
            #pragma unroll
            for (int q = 0; q < 4; ++q) {
                const float* bb = (q==0)?sL:(q==1)?sH:(q==2)?cL:cH;
                const int blk = cc*4 + q;
                float v[8];
                #pragma unroll
                for (int i = 0; i < 8; ++i) {
                    const int dim = blk*32 + seg*8 + i;
                    const float4 wv = *(const float4*)W4[dim];
                    v[i] = fmaf(f0, wv.x, fmaf(f1, wv.y, fmaf(f2, wv.z, bb[i] + wv.w)));
                }
                *(bf16x8*)&snxb[(size_t)(eb*64 + er)*HIDDEN + blk*32 + seg*8] = pack8(v);
            }
        }
        return;
    }
    // ---- repack: frag (kt,nt): lane l elem j = W[kt*32+(l>>4)*8+j][nt*16+(l&15)]
    const int grp = b / 72, sub = b % 72;
    const float* W; unsigned short* out;
    switch (grp) {
        case 0: W = W1;              out = w1sf; break;
        case 1: W = W1 + 384*HIDDEN; out = w1df; break;
        case 2: W = W2;              out = w2f;  break;
        case 3: W = Wp;              out = wpf;  break;
        default:W = Wp + 384*HIDDEN; out = wpf + WBLK; break;
    }
    const int idx = sub * 256 + t;   // 72*256 == FRAGS exactly
    const int l   = idx & 63;
    const int frag= idx >> 6;
    const int nt  = frag % 24;
    const int kt  = frag / 24;
    const int col = nt * 16 + (l & 15);
    const int k0  = kt * 32 + (l >> 4) * 8;
    unsigned int pk[4];
    #pragma unroll
    for (int j = 0; j < 4; ++j) {
        unsigned int lo = f2bf(W[(k0 + 2*j)     * HIDDEN + col]);
        unsigned int hi = f2bf(W[(k0 + 2*j + 1) * HIDDEN + col]);
        pk[j] = lo | (hi << 16);
    }
    *reinterpret_cast<uint4*>(&out[(size_t)idx * 8]) =
        *reinterpret_cast<const uint4*>(pk);
}

// ---- K2: fused edge MLP with K=768 layer 1 ----
// 256 thr (4 waves), 64 edges (2 sn)/block, grid 1024.
// Layer 1 = dst-half (12 kt, A = snxb broadcast loads, B = w1df, NO LDS,
// interleaved barrier-free with the embed VALU) + src-half (12 kt from
// frag-major G in LDS, B = w1sf). k_dstv kernel is gone.
__global__ __launch_bounds__(256, 2)
void k_mlp(const float* __restrict__ pos, const float* __restrict__ feat,
           const int* __restrict__ nbr_idx, const void* __restrict__ mask_raw,
           const int* __restrict__ mask_fmt,
           const float* __restrict__ W_in, const float* __restrict__ b_in,
           const unsigned short* __restrict__ snxb,
           const unsigned short* __restrict__ W1sf,
           const unsigned short* __restrict__ W1df,
           const unsigned short* __restrict__ W2f,
           const float* __restrict__ b1, const float* __restrict__ b2,
           unsigned short* __restrict__ aggb)
{
    __shared__ unsigned short G[4*12*64*8];   // 49152 B frag-major
    __shared__ ushort4 WINTB[HIDDEN];         // 3072 B bf16 {w0,w1,w2,b}
    __shared__ float PF[64][7];               // 1792 B pos3,feat3,mval
    __shared__ float CNT[2];

    const int t  = threadIdx.x;
    const int bm = blockIdx.x;
    const int l = t & 63, ng = t >> 6, lg = l >> 4, l15 = l & 15;

    bf16x8 bA[6], bB[6];
    #define LOADB(dst, Wf, kt)                                                  \
        { const unsigned short* bp_ = &Wf[((size_t)((kt)*24 + ng*6)*64 + l)*8]; \
          _Pragma("unroll")                                                     \
          for (int nt_ = 0; nt_ < 6; ++nt_)                                     \
              dst[nt_] = *(const bf16x8*)(bp_ + (size_t)nt_*512); }
    #define AREAD(a_, kt)                                                       \
        { _Pragma("unroll")                                                     \
          for (int mt_ = 0; mt_ < 4; ++mt_)                                     \
              a_[mt_] = *(const bf16x8*)&G[(size_t)(((mt_*12 + (kt))*64) + l)*8]; }
    #define MFMA6(bfr, a_)                                                      \
        { __builtin_amdgcn_s_setprio(1);                                        \
          _Pragma("unroll")                                                     \
          for (int mt_ = 0; mt_ < 4; ++mt_)                                     \
              _Pragma("unroll")                                                 \
              for (int nt_ = 0; nt_ < 6; ++nt_)                                 \
                  acc[mt_][nt_] = __builtin_amdgcn_mfma_f32_16x16x32_bf16(      \
                      a_[mt_], bfr[nt_], acc[mt_][nt_], 0, 0, 0);               \
          __builtin_amdgcn_s_setprio(0); }

    if (t < 64) {
        const int e  = bm*64 + t;
        const int pi = nbr_idx[e];
        PF[t][0]=pos[pi*3];  PF[t][1]=pos[pi*3+1];  PF[t][2]=pos[pi*3+2];
        PF[t][3]=feat[pi*3]; PF[t][4]=feat[pi*3+1]; PF[t][5]=feat[pi*3+2];
        const int fmt = *mask_fmt;
        const int mv  = fmt ? (int)((const unsigned char*)mask_raw)[e]
                            : ((const int*)mask_raw)[e];
        PF[t][6] = mv ? 1.0f : 0.0f;
    }
    for (int d = t; d < HIDDEN; d += 256) {
        ushort4 wv;
        wv.x = f2bf(W_in[d]); wv.y = f2bf(W_in[HIDDEN+d]);
        wv.z = f2bf(W_in[2*HIDDEN+d]); wv.w = f2bf(b_in[d]);
        WINTB[d] = wv;
    }
    // b1 slice for the gelu epilogue (col = ng*96 + nt*16 + l15)
    float b1r[6];
    #pragma unroll
    for (int nt = 0; nt < 6; ++nt) b1r[nt] = b1[ng*96 + nt*16 + l15];
    __syncthreads();
    if (t < 2) {
        float c = 0.f;
        for (int s = 0; s < 32; ++s) c += PF[t*32+s][6];
        CNT[t] = c;   // read after later barriers
    }

    // ---- per-thread embed state (row er, 8-dim group seg within each 32) ----
    const int er = t >> 2, seg = t & 3;
    float frA[8], frB[8];
    #pragma unroll
    for (int i = 0; i < 8; ++i) {
        frA[i] = exp2f(-(float)(seg*8 + i)      * 0.2076205059304601f);
        frB[i] = exp2f(-(float)(32 + seg*8 + i) * 0.2076205059304601f);
    }
    const float f0 = PF[er][3], f1 = PF[er][4], f2 = PF[er][5];
    const float pc0 = PF[er][0], pc1 = PF[er][1], pc2 = PF[er][2];
    const int slotbase = (er>>4)*12*64 + seg*16 + (er&15);

    #define EMB(kt_)                                                            \
        { const float pc = ((kt_)>>2)==0 ? pc0 : (((kt_)>>2)==1 ? pc1 : pc2);   \
          float v[8];                                                           \
          _Pragma("unroll")                                                     \
          for (int i = 0; i < 8; ++i) {                                         \
              const float fr = ((kt_)&1) ? frB[i] : frA[i];                     \
              const float aa = pc * fr;                                         \
              const float base = (((kt_)>>1)&1) ? __cosf(aa) : __sinf(aa);      \
              const ushort4 wv = WINTB[(kt_)*32 + seg*8 + i];                   \
              v[i] = fmaf(f0, b2f(wv.x), fmaf(f1, b2f(wv.y),                    \
                     fmaf(f2, b2f(wv.z), base + b2f(wv.w))));                   \
          }                                                                     \
          *(bf16x8*)&G[(size_t)(slotbase + (kt_)*64)*8] = pack8(v); }

    f32x4 acc[4][6];
    #pragma unroll
    for (int mt=0; mt<4; ++mt)
        #pragma unroll
        for (int nt=0; nt<6; ++nt) acc[mt][nt] = (f32x4){0.f,0.f,0.f,0.f};

    // ---- phase A: dst-half GEMM (no LDS dep) interleaved with embed, 0 barriers.
    // A-frag for a dst k-tile is wave-uniform per 16-lane group: all rows of an
    // m-tile belong to ONE supernode -> one bf16x8 broadcast load from snxb.
    const unsigned short* snx0 = &snxb[(size_t)(bm*2 + 0)*HIDDEN];
    const unsigned short* snx1 = &snxb[(size_t)(bm*2 + 1)*HIDDEN];
    #pragma unroll
    for (int kt = 0; kt < 12; ++kt) {
        LOADB(bA, W1df, kt);
        bf16x8 s0 = *(const bf16x8*)&snx0[kt*32 + lg*8];
        bf16x8 s1 = *(const bf16x8*)&snx1[kt*32 + lg*8];
        EMB(kt);   // ~220 cyc of VALU covers the load latency; MFMA overlaps
        __builtin_amdgcn_s_setprio(1);
        #pragma unroll
        for (int nt = 0; nt < 6; ++nt) {
            acc[0][nt] = __builtin_amdgcn_mfma_f32_16x16x32_bf16(s0, bA[nt], acc[0][nt], 0,0,0);
            acc[1][nt] = __builtin_amdgcn_mfma_f32_16x16x32_bf16(s0, bA[nt], acc[1][nt], 0,0,0);
            acc[2][nt] = __builtin_amdgcn_mfma_f32_16x16x32_bf16(s1, bA[nt], acc[2][nt], 0,0,0);
            acc[3][nt] = __builtin_amdgcn_mfma_f32_16x16x32_bf16(s1, bA[nt], acc[3][nt], 0,0,0);
        }
        __builtin_amdgcn_s_setprio(0);
    }
    __syncthreads();   // G complete

    // ---- phase B: src-half GEMM from LDS, B 2-deep prefetch ----
    LOADB(bA, W1sf, 0); LOADB(bB, W1sf, 1);
    #pragma unroll
    for (int kt = 0; kt < 12; kt += 2) {
        bf16x8 a[4];
        AREAD(a, kt);
        MFMA6(bA, a);
        if (kt + 2 < 12) LOADB(bA, W1sf, kt + 2);
        AREAD(a, kt + 1);
        MFMA6(bB, a);
        if (kt + 3 < 12) LOADB(bB, W1sf, kt + 3);
    }
    __syncthreads();   // all G reads done

    // ---- gelu epilogue: +b1, gelu, scatter bf16 into frag-major G ----
    #pragma unroll
    for (int mt=0; mt<4; ++mt) {
        #pragma unroll
        for (int nt=0; nt<6; ++nt) {
            const int col = ng*96 + nt*16 + l15;
            const float bb1 = b1r[nt];
            const int base = ((mt*12 + (col>>5))*64 + ((col>>3)&3)*16 + lg*4)*8 + (col&7);
            #pragma unroll
            for (int r=0; r<4; ++r)
                G[base + r*8] = f2bf(gelu(acc[mt][nt][r] + bb1));
        }
    }
    __syncthreads();

    // ---- layer 2: Y2 = G @ W2 ----
    #pragma unroll
    for (int mt=0; mt<4; ++mt)
        #pragma unroll
        for (int nt=0; nt<6; ++nt) acc[mt][nt] = (f32x4){0.f,0.f,0.f,0.f};
    LOADB(bA, W2f, 0); LOADB(bB, W2f, 1);
    #pragma unroll
    for (int kt = 0; kt < 12; kt += 2) {
        bf16x8 a[4];
        AREAD(a, kt);
        MFMA6(bA, a);
        if (kt + 2 < 12) LOADB(bA, W2f, kt + 2);
        AREAD(a, kt + 1);
        MFMA6(bB, a);
        if (kt + 3 < 12) LOADB(bB, W2f, kt + 3);
    }

    // ---- masked mean -> aggb (bf16, b2 folded) ----
    #pragma unroll
    for (int nt=0; nt<6; ++nt) {
        const int col = ng*96 + nt*16 + l15;
        float s0 = 0.f, s1 = 0.f;
        #pragma unroll
        for (int mt=0; mt<4; ++mt) {
            float p = 0.f;
            #pragma unroll
            for (int r=0; r<4; ++r)
                p += PF[mt*16 + lg*4 + r][6] * acc[mt][nt][r];
            if (mt < 2) s0 += p; else s1 += p;
        }
        s0 += __shfl_xor(s0,16); s0 += __shfl_xor(s0,32);
        s1 += __shfl_xor(s1,16); s1 += __shfl_xor(s1,32);
        if (lg == 0) {
            const float bb = b2[col];
            const int sn0 = bm*2;
            const float c0 = CNT[0], c1 = CNT[1];
            aggb[(size_t)sn0*HIDDEN + col]     = f2bf(s0 / fmaxf(c0,1.f) + bb*(c0>0.f?1.f:0.f));
            aggb[(size_t)(sn0+1)*HIDDEN + col] = f2bf(s1 / fmaxf(c1,1.f) + bb*(c1>0.f?1.f:0.f));
        }
    }
    #undef LOADB
    #undef AREAD
    #undef MFMA6
    #undef EMB
}

// ---- K3: projection out = [aggb|snxb] @ Wp + bp. 128 blocks = 32 rg x 4 cq ----
__global__ __launch_bounds__(256)
void k_proj(const unsigned short* __restrict__ aggb,
            const unsigned short* __restrict__ snxb,
            const unsigned short* __restrict__ wpf,
            const float* __restrict__ bp, float* __restrict__ out) {
    const int rg = blockIdx.x >> 2, cq = blockIdx.x & 3;
    const int t = threadIdx.x, w = t>>6, l = t&63, lg = l>>4, l15 = l&15;
    const int wgm = w>>1, wgn = w&1;
    const int r0 = rg*64 + wgm*32;
    const int ntb = cq*6 + wgn*3;
    f32x4 acc[2][3];
    #pragma unroll
    for (int mt=0; mt<2; ++mt)
        #pragma unroll
        for (int nt=0; nt<3; ++nt) acc[mt][nt] = (f32x4){0.f,0.f,0.f,0.f};
    #pragma unroll 2
    for (int kt = 0; kt < 24; ++kt) {
        const unsigned short* Ab = (kt < 12) ? aggb : snxb;
        const unsigned short* Wb = (kt < 12) ? wpf  : wpf + WBLK;
        const int ktt = (kt < 12) ? kt : kt - 12;
        bf16x8 a[2], bfr[3];
        const unsigned short* bpp = &Wb[((size_t)(ktt*24 + ntb)*64 + l)*8];
        #pragma unroll
        for (int nt=0; nt<3; ++nt) bfr[nt] = *(const bf16x8*)(bpp + (size_t)nt*512);
        #pragma unroll
        for (int mt=0; mt<2; ++mt)
            a[mt] = *(const bf16x8*)&Ab[(size_t)(r0 + mt*16 + l15)*HIDDEN + ktt*32 + lg*8];
        #pragma unroll
        for (int mt=0; mt<2; ++mt)
            #pragma unroll
            for (int nt=0; nt<3; ++nt)
                acc[mt][nt] = __builtin_amdgcn_mfma_f32_16x16x32_bf16(a[mt], bfr[nt], acc[mt][nt], 0,0,0);
    }
    #pragma unroll
    for (int mt=0; mt<2; ++mt)
        #pragma unroll
        for (int nt=0; nt<3; ++nt) {
            const int col = cq*96 + wgn*48 + nt*16 + l15;
            #pragma unroll
            for (int r=0; r<4; ++r) {
                const int row = r0 + mt*16 + lg*4 + r;
                out[(size_t)row*HIDDEN + col] = acc[mt][nt][r] + bp[col];
            }
        }
}

extern "C" void kernel_launch(void* const* d_in, const int* in_sizes, int n_in,
                              void* d_out, int out_size, void* d_ws, size_t ws_size,
                              hipStream_t stream) {
    const float* pos   = (const float*)d_in[0];
    const float* feat  = (const float*)d_in[1];
    const int*   sn    = (const int*)d_in[2];
    const int*   nbr   = (const int*)d_in[3];
    const void*  mask  = d_in[4];
    const float* W_in  = (const float*)d_in[5];
    const float* b_in  = (const float*)d_in[6];
    const float* W1    = (const float*)d_in[7];
    const float* b1    = (const float*)d_in[8];
    const float* W2    = (const float*)d_in[9];
    const float* b2    = (const float*)d_in[10];
    const float* Wp    = (const float*)d_in[11];
    const float* bpv   = (const float*)d_in[12];
    float* out = (float*)d_out;

    char* base = (char*)d_ws;
    int* flag = (int*)base;
    unsigned short* w1sf = (unsigned short*)(base + 256);
    unsigned short* w1df = w1sf + WBLK;
    unsigned short* w2f  = w1df + WBLK;
    unsigned short* wpf  = w2f  + WBLK;                  // 2 blocks (768 rows)
    unsigned short* snxb = wpf  + 2*(size_t)WBLK;        // 2048*384 bf16
    unsigned short* aggb = snxb + (size_t)NSUPER*HIDDEN;

    hipLaunchKernelGGL(prep, dim3(393), dim3(256), 0, stream,
                       W1, W2, Wp, (const unsigned int*)mask,
                       pos, feat, sn, W_in, b_in,
                       w1sf, w1df, w2f, wpf, snxb, flag);
    hipLaunchKernelGGL(k_mlp, dim3(1024), dim3(256), 0, stream,
                       pos, feat, nbr, mask, flag, W_in, b_in,
                       snxb, w1sf, w1df, w2f, b1, b2, aggb);
    hipLaunchKernelGGL(k_proj, dim3(128), dim3(256), 0, stream,
                       aggb, snxb, wpf, bpv, out);
}

// Round 11
// 81.170 us; speedup vs baseline: 1.1117x; 1.0403x over previous
//
#include <hip/hip_runtime.h>
#include <hip/hip_bf16.h>
#include <cstdint>

#define HIDDEN 384
#define NSUPER 2048
#define MAXDEG 32
#define FRAGS (12*24*64)            // fragments*lanes per 384x384 block
#define WBLK  (FRAGS*8)             // shorts per repacked 384x384 block = 147456

typedef __attribute__((ext_vector_type(8))) short bf16x8;
typedef __attribute__((ext_vector_type(4))) float f32x4;

// branchless RNE f32->bf16 (finite values only; ~4 VALU ops)
__device__ inline unsigned short f2bf(float f) {
    unsigned int u = __float_as_uint(f);
    return (unsigned short)((u + 0x7fffu + ((u >> 16) & 1u)) >> 16);
}
__device__ inline float b2f(unsigned short s) {
    return __uint_as_float(((unsigned int)s) << 16);
}
__device__ inline bf16x8 pack8(const float* v) {
    union { bf16x8 v8; unsigned short u[8]; } u;
    #pragma unroll
    for (int i = 0; i < 8; ++i) u.u[i] = f2bf(v[i]);
    return u.v8;
}
// tanh-form gelu as y*sigmoid(2u): ~9 VALU ops, |err| <= ~1e-3 on gelu
__device__ inline float gelu(float y) {
    const float y2 = y * y;
    const float m  = __expf(y * fmaf(-0.0713548163f, y2, -1.5957691216f));
    return y * (1.0f / (1.0f + m));
}

// ---- K1: weight repacks + mask detect + supernode embeds, ONE launch ----
__global__ __launch_bounds__(256)
void prep(const float* __restrict__ W1, const float* __restrict__ W2,
          const float* __restrict__ Wp, const unsigned int* __restrict__ mask,
          const float* __restrict__ pos, const float* __restrict__ feat,
          const int* __restrict__ sn_idx,
          const float* __restrict__ W_in, const float* __restrict__ b_in,
          unsigned short* __restrict__ w1sf, unsigned short* __restrict__ w1df,
          unsigned short* __restrict__ w2f,  unsigned short* __restrict__ wpf,
          unsigned short* __restrict__ snxb, int* __restrict__ flag) {
    const int b = blockIdx.x;
    const int t = threadIdx.x;
    if (b == 360) {   // mask detect: uint8 numpy-bool vs int32
        __shared__ int s;
        if (t == 0) s = 0;
        __syncthreads();
        int bad = 0;
        for (int i = t; i < 16384; i += 256)
            if (mask[i] > 1u) bad = 1;
        if (bad) s = 1;
        __syncthreads();
        if (t == 0) *flag = s;   // 1 => uint8, 0 => int32
        return;
    }
    if (b > 360) {    // ---- supernode embeds -> snxb ----
        __shared__ float W4[HIDDEN][4];
        __shared__ float P6[64][7];
        const int eb = b - 361;   // 0..31
        if (t < 64) {
            const int pi = sn_idx[eb*64 + t];
            P6[t][0]=pos[pi*3];  P6[t][1]=pos[pi*3+1];  P6[t][2]=pos[pi*3+2];
            P6[t][3]=feat[pi*3]; P6[t][4]=feat[pi*3+1]; P6[t][5]=feat[pi*3+2];
        }
        for (int d = t; d < HIDDEN; d += 256) {
            W4[d][0]=W_in[d]; W4[d][1]=W_in[HIDDEN+d];
            W4[d][2]=W_in[2*HIDDEN+d]; W4[d][3]=b_in[d];
        }
        __syncthreads();
        const int er = t >> 2, seg = t & 3;
        float frA[8], frB[8];
        #pragma unroll
        for (int i = 0; i < 8; ++i) {
            frA[i] = exp2f(-(float)(seg*8 + i)      * 0.2076205059304601f);
            frB[i] = exp2f(-(float)(32 + seg*8 + i) * 0.2076205059304601f);
        }
        const float f0 = P6[er][3], f1 = P6[er][4], f2 = P6[er][5];
        #pragma unroll
        for (int cc = 0; cc < 3; ++cc) {
            const float pc = P6[er][cc];
            float sL[8], sH[8], cL[8], cH[8];
            #pragma unroll
            for (int i = 0; i < 8; ++i) {
                const float aL = pc*frA[i], aH = pc*frB[i];
                sL[i]=__sinf(aL); sH[i]=__sinf(aH); cL[i]=__cosf(aL); cH[i]=__cosf(aH);
            }
            #pragma unroll
            for (int q = 0; q < 4; ++q) {
                const float* bb = (q==0)?sL:(q==1)?sH:(q==2)?cL:cH;
                const int blk = cc*4 + q;
                float v[8];
                #pragma unroll
                for (int i = 0; i < 8; ++i) {
                    const int dim = blk*32 + seg*8 + i;
                    const float4 wv = *(const float4*)W4[dim];
                    v[i] = fmaf(f0, wv.x, fmaf(f1, wv.y, fmaf(f2, wv.z, bb[i] + wv.w)));
                }
                *(bf16x8*)&snxb[(size_t)(eb*64 + er)*HIDDEN + blk*32 + seg*8] = pack8(v);
            }
        }
        return;
    }
    // ---- repack: frag (kt,nt): lane l elem j = W[kt*32+(l>>4)*8+j][nt*16+(l&15)]
    const int grp = b / 72, sub = b % 72;
    const float* W; unsigned short* out;
    switch (grp) {
        case 0: W = W1;              out = w1sf; break;
        case 1: W = W1 + 384*HIDDEN; out = w1df; break;
        case 2: W = W2;              out = w2f;  break;
        case 3: W = Wp;              out = wpf;  break;
        default:W = Wp + 384*HIDDEN; out = wpf + WBLK; break;
    }
    const int idx = sub * 256 + t;   // 72*256 == FRAGS exactly
    const int l   = idx & 63;
    const int frag= idx >> 6;
    const int nt  = frag % 24;
    const int kt  = frag / 24;
    const int col = nt * 16 + (l & 15);
    const int k0  = kt * 32 + (l >> 4) * 8;
    unsigned int pk[4];
    #pragma unroll
    for (int j = 0; j < 4; ++j) {
        unsigned int lo = f2bf(W[(k0 + 2*j)     * HIDDEN + col]);
        unsigned int hi = f2bf(W[(k0 + 2*j + 1) * HIDDEN + col]);
        pk[j] = lo | (hi << 16);
    }
    *reinterpret_cast<uint4*>(&out[(size_t)idx * 8]) =
        *reinterpret_cast<const uint4*>(pk);
}

// ---- K2: fused edge MLP, layer 1 only + gelu + masked mean ----
// Mean-before-W2 algebra: agg = ((sum_n m_n g_n)/cnt) @ W2 + b2*nz, so this
// kernel stops at aggpre = (sum m g)/cnt. Layer-2 (19.3 GFLOP over edges)
// becomes k_agg (1.2 GFLOP over supernodes): 16x FLOP cut, and the gelu->LDS
// scatter (bank-conflict source) + a barrier pair disappear.
__global__ __launch_bounds__(256, 2)
void k_mlp(const float* __restrict__ pos, const float* __restrict__ feat,
           const int* __restrict__ nbr_idx, const void* __restrict__ mask_raw,
           const int* __restrict__ mask_fmt,
           const float* __restrict__ W_in, const float* __restrict__ b_in,
           const unsigned short* __restrict__ snxb,
           const unsigned short* __restrict__ W1sf,
           const unsigned short* __restrict__ W1df,
           const float* __restrict__ b1,
           unsigned short* __restrict__ aggpre, float* __restrict__ cntf)
{
    __shared__ unsigned short G[4*12*64*8];   // 49152 B frag-major embeds
    __shared__ ushort4 WINTB[HIDDEN];         // 3072 B bf16 {w0,w1,w2,b}
    __shared__ float PF[64][7];               // 1792 B pos3,feat3,mval
    __shared__ float CNT[2];

    const int t  = threadIdx.x;
    const int bm = blockIdx.x;
    const int l = t & 63, ng = t >> 6, lg = l >> 4, l15 = l & 15;

    bf16x8 bA[6], bB[6];
    #define LOADB(dst, Wf, kt)                                                  \
        { const unsigned short* bp_ = &Wf[((size_t)((kt)*24 + ng*6)*64 + l)*8]; \
          _Pragma("unroll")                                                     \
          for (int nt_ = 0; nt_ < 6; ++nt_)                                     \
              dst[nt_] = *(const bf16x8*)(bp_ + (size_t)nt_*512); }
    #define AREAD(a_, kt)                                                       \
        { _Pragma("unroll")                                                     \
          for (int mt_ = 0; mt_ < 4; ++mt_)                                     \
              a_[mt_] = *(const bf16x8*)&G[(size_t)(((mt_*12 + (kt))*64) + l)*8]; }
    #define MFMA6(bfr, a_)                                                      \
        { __builtin_amdgcn_s_setprio(1);                                        \
          _Pragma("unroll")                                                     \
          for (int mt_ = 0; mt_ < 4; ++mt_)                                     \
              _Pragma("unroll")                                                 \
              for (int nt_ = 0; nt_ < 6; ++nt_)                                 \
                  acc[mt_][nt_] = __builtin_amdgcn_mfma_f32_16x16x32_bf16(      \
                      a_[mt_], bfr[nt_], acc[mt_][nt_], 0, 0, 0);               \
          __builtin_amdgcn_s_setprio(0); }

    if (t < 64) {
        const int e  = bm*64 + t;
        const int pi = nbr_idx[e];
        PF[t][0]=pos[pi*3];  PF[t][1]=pos[pi*3+1];  PF[t][2]=pos[pi*3+2];
        PF[t][3]=feat[pi*3]; PF[t][4]=feat[pi*3+1]; PF[t][5]=feat[pi*3+2];
        const int fmt = *mask_fmt;
        const int mv  = fmt ? (int)((const unsigned char*)mask_raw)[e]
                            : ((const int*)mask_raw)[e];
        PF[t][6] = mv ? 1.0f : 0.0f;
    }
    for (int d = t; d < HIDDEN; d += 256) {
        ushort4 wv;
        wv.x = f2bf(W_in[d]); wv.y = f2bf(W_in[HIDDEN+d]);
        wv.z = f2bf(W_in[2*HIDDEN+d]); wv.w = f2bf(b_in[d]);
        WINTB[d] = wv;
    }
    // b1 slice (col = ng*96 + nt*16 + l15) for the gelu epilogue
    float b1r[6];
    #pragma unroll
    for (int nt = 0; nt < 6; ++nt) b1r[nt] = b1[ng*96 + nt*16 + l15];
    __syncthreads();
    if (t < 2) {
        float c = 0.f;
        for (int s = 0; s < 32; ++s) c += PF[t*32+s][6];
        CNT[t] = c;   // read after the phase-A barrier
    }

    // ---- per-thread embed state (row er, 8-dim group seg within each 32) ----
    const int er = t >> 2, seg = t & 3;
    float frA[8], frB[8];
    #pragma unroll
    for (int i = 0; i < 8; ++i) {
        frA[i] = exp2f(-(float)(seg*8 + i)      * 0.2076205059304601f);
        frB[i] = exp2f(-(float)(32 + seg*8 + i) * 0.2076205059304601f);
    }
    const float f0 = PF[er][3], f1 = PF[er][4], f2 = PF[er][5];
    const float pc0 = PF[er][0], pc1 = PF[er][1], pc2 = PF[er][2];
    const int slotbase = (er>>4)*12*64 + seg*16 + (er&15);

    #define EMB(kt_)                                                            \
        { const float pc = ((kt_)>>2)==0 ? pc0 : (((kt_)>>2)==1 ? pc1 : pc2);   \
          float v[8];                                                           \
          _Pragma("unroll")                                                     \
          for (int i = 0; i < 8; ++i) {                                         \
              const float fr = ((kt_)&1) ? frB[i] : frA[i];                     \
              const float aa = pc * fr;                                         \
              const float base = (((kt_)>>1)&1) ? __cosf(aa) : __sinf(aa);      \
              const ushort4 wv = WINTB[(kt_)*32 + seg*8 + i];                   \
              v[i] = fmaf(f0, b2f(wv.x), fmaf(f1, b2f(wv.y),                    \
                     fmaf(f2, b2f(wv.z), base + b2f(wv.w))));                   \
          }                                                                     \
          *(bf16x8*)&G[(size_t)(slotbase + (kt_)*64)*8] = pack8(v); }

    f32x4 acc[4][6];
    #pragma unroll
    for (int mt=0; mt<4; ++mt)
        #pragma unroll
        for (int nt=0; nt<6; ++nt) acc[mt][nt] = (f32x4){0.f,0.f,0.f,0.f};

    // ---- phase A: dst-half GEMM (snxb broadcast A, no LDS dep) interleaved
    // with the embed VALU, 0 barriers ----
    const unsigned short* snx0 = &snxb[(size_t)(bm*2 + 0)*HIDDEN];
    const unsigned short* snx1 = &snxb[(size_t)(bm*2 + 1)*HIDDEN];
    #pragma unroll
    for (int kt = 0; kt < 12; ++kt) {
        LOADB(bA, W1df, kt);
        bf16x8 s0 = *(const bf16x8*)&snx0[kt*32 + lg*8];
        bf16x8 s1 = *(const bf16x8*)&snx1[kt*32 + lg*8];
        EMB(kt);
        __builtin_amdgcn_s_setprio(1);
        #pragma unroll
        for (int nt = 0; nt < 6; ++nt) {
            acc[0][nt] = __builtin_amdgcn_mfma_f32_16x16x32_bf16(s0, bA[nt], acc[0][nt], 0,0,0);
            acc[1][nt] = __builtin_amdgcn_mfma_f32_16x16x32_bf16(s0, bA[nt], acc[1][nt], 0,0,0);
            acc[2][nt] = __builtin_amdgcn_mfma_f32_16x16x32_bf16(s1, bA[nt], acc[2][nt], 0,0,0);
            acc[3][nt] = __builtin_amdgcn_mfma_f32_16x16x32_bf16(s1, bA[nt], acc[3][nt], 0,0,0);
        }
        __builtin_amdgcn_s_setprio(0);
    }
    __syncthreads();   // G complete (also orders CNT)

    // ---- phase B: src-half GEMM from LDS, B 2-deep prefetch ----
    LOADB(bA, W1sf, 0); LOADB(bB, W1sf, 1);
    #pragma unroll
    for (int kt = 0; kt < 12; kt += 2) {
        bf16x8 a[4];
        AREAD(a, kt);
        MFMA6(bA, a);
        if (kt + 2 < 12) LOADB(bA, W1sf, kt + 2);
        AREAD(a, kt + 1);
        MFMA6(bB, a);
        if (kt + 3 < 12) LOADB(bB, W1sf, kt + 3);
    }

    // ---- gelu + masked mean -> aggpre (bf16); no LDS scatter, no layer-2 ----
    #pragma unroll
    for (int nt=0; nt<6; ++nt) {
        const int col = ng*96 + nt*16 + l15;
        const float bb1 = b1r[nt];
        float s0 = 0.f, s1 = 0.f;
        #pragma unroll
        for (int mt=0; mt<4; ++mt) {
            float p = 0.f;
            #pragma unroll
            for (int r=0; r<4; ++r)
                p += PF[mt*16 + lg*4 + r][6] * gelu(acc[mt][nt][r] + bb1);
            if (mt < 2) s0 += p; else s1 += p;
        }
        s0 += __shfl_xor(s0,16); s0 += __shfl_xor(s0,32);
        s1 += __shfl_xor(s1,16); s1 += __shfl_xor(s1,32);
        if (lg == 0) {
            const int sn0 = bm*2;
            aggpre[(size_t)sn0*HIDDEN + col]     = f2bf(s0 / fmaxf(CNT[0],1.f));
            aggpre[(size_t)(sn0+1)*HIDDEN + col] = f2bf(s1 / fmaxf(CNT[1],1.f));
        }
    }
    if (t < 2) cntf[bm*2 + t] = CNT[t];
    #undef LOADB
    #undef AREAD
    #undef MFMA6
    #undef EMB
}

// ---- K3: aggb = aggpre @ W2 + b2*(cnt>0). 128 blocks = 32 rg x 4 cq ----
__global__ __launch_bounds__(256)
void k_agg(const unsigned short* __restrict__ aggpre,
           const unsigned short* __restrict__ w2f,
           const float* __restrict__ b2, const float* __restrict__ cntf,
           unsigned short* __restrict__ aggb) {
    const int rg = blockIdx.x >> 2, cq = blockIdx.x & 3;
    const int t = threadIdx.x, w = t>>6, l = t&63, lg = l>>4, l15 = l&15;
    const int wgm = w>>1, wgn = w&1;
    const int r0 = rg*64 + wgm*32;
    const int ntb = cq*6 + wgn*3;
    f32x4 acc[2][3];
    #pragma unroll
    for (int mt=0; mt<2; ++mt)
        #pragma unroll
        for (int nt=0; nt<3; ++nt) acc[mt][nt] = (f32x4){0.f,0.f,0.f,0.f};
    #pragma unroll 2
    for (int kt = 0; kt < 12; ++kt) {
        bf16x8 a[2], bfr[3];
        const unsigned short* bpp = &w2f[((size_t)(kt*24 + ntb)*64 + l)*8];
        #pragma unroll
        for (int nt=0; nt<3; ++nt) bfr[nt] = *(const bf16x8*)(bpp + (size_t)nt*512);
        #pragma unroll
        for (int mt=0; mt<2; ++mt)
            a[mt] = *(const bf16x8*)&aggpre[(size_t)(r0 + mt*16 + l15)*HIDDEN + kt*32 + lg*8];
        #pragma unroll
        for (int mt=0; mt<2; ++mt)
            #pragma unroll
            for (int nt=0; nt<3; ++nt)
                acc[mt][nt] = __builtin_amdgcn_mfma_f32_16x16x32_bf16(a[mt], bfr[nt], acc[mt][nt], 0,0,0);
    }
    #pragma unroll
    for (int mt=0; mt<2; ++mt)
        #pragma unroll
        for (int nt=0; nt<3; ++nt) {
            const int col = cq*96 + wgn*48 + nt*16 + l15;
            const float bb = b2[col];
            #pragma unroll
            for (int r=0; r<4; ++r) {
                const int row = r0 + mt*16 + lg*4 + r;
                const float nz = (cntf[row] > 0.f) ? 1.f : 0.f;
                aggb[(size_t)row*HIDDEN + col] = f2bf(acc[mt][nt][r] + bb*nz);
            }
        }
}

// ---- K4: projection out = [aggb|snxb] @ Wp + bp. 128 blocks = 32 rg x 4 cq ----
__global__ __launch_bounds__(256)
void k_proj(const unsigned short* __restrict__ aggb,
            const unsigned short* __restrict__ snxb,
            const unsigned short* __restrict__ wpf,
            const float* __restrict__ bp, float* __restrict__ out) {
    const int rg = blockIdx.x >> 2, cq = blockIdx.x & 3;
    const int t = threadIdx.x, w = t>>6, l = t&63, lg = l>>4, l15 = l&15;
    const int wgm = w>>1, wgn = w&1;
    const int r0 = rg*64 + wgm*32;
    const int ntb = cq*6 + wgn*3;
    f32x4 acc[2][3];
    #pragma unroll
    for (int mt=0; mt<2; ++mt)
        #pragma unroll
        for (int nt=0; nt<3; ++nt) acc[mt][nt] = (f32x4){0.f,0.f,0.f,0.f};
    #pragma unroll 2
    for (int kt = 0; kt < 24; ++kt) {
        const unsigned short* Ab = (kt < 12) ? aggb : snxb;
        const unsigned short* Wb = (kt < 12) ? wpf  : wpf + WBLK;
        const int ktt = (kt < 12) ? kt : kt - 12;
        bf16x8 a[2], bfr[3];
        const unsigned short* bpp = &Wb[((size_t)(ktt*24 + ntb)*64 + l)*8];
        #pragma unroll
        for (int nt=0; nt<3; ++nt) bfr[nt] = *(const bf16x8*)(bpp + (size_t)nt*512);
        #pragma unroll
        for (int mt=0; mt<2; ++mt)
            a[mt] = *(const bf16x8*)&Ab[(size_t)(r0 + mt*16 + l15)*HIDDEN + ktt*32 + lg*8];
        #pragma unroll
        for (int mt=0; mt<2; ++mt)
            #pragma unroll
            for (int nt=0; nt<3; ++nt)
                acc[mt][nt] = __builtin_amdgcn_mfma_f32_16x16x32_bf16(a[mt], bfr[nt], acc[mt][nt], 0,0,0);
    }
    #pragma unroll
    for (int mt=0; mt<2; ++mt)
        #pragma unroll
        for (int nt=0; nt<3; ++nt) {
            const int col = cq*96 + wgn*48 + nt*16 + l15;
            #pragma unroll
            for (int r=0; r<4; ++r) {
                const int row = r0 + mt*16 + lg*4 + r;
                out[(size_t)row*HIDDEN + col] = acc[mt][nt][r] + bp[col];
            }
        }
}

extern "C" void kernel_launch(void* const* d_in, const int* in_sizes, int n_in,
                              void* d_out, int out_size, void* d_ws, size_t ws_size,
                              hipStream_t stream) {
    const float* pos   = (const float*)d_in[0];
    const float* feat  = (const float*)d_in[1];
    const int*   sn    = (const int*)d_in[2];
    const int*   nbr   = (const int*)d_in[3];
    const void*  mask  = d_in[4];
    const float* W_in  = (const float*)d_in[5];
    const float* b_in  = (const float*)d_in[6];
    const float* W1    = (const float*)d_in[7];
    const float* b1    = (const float*)d_in[8];
    const float* W2    = (const float*)d_in[9];
    const float* b2    = (const float*)d_in[10];
    const float* Wp    = (const float*)d_in[11];
    const float* bpv   = (const float*)d_in[12];
    float* out = (float*)d_out;

    char* base = (char*)d_ws;
    int* flag = (int*)base;
    unsigned short* w1sf = (unsigned short*)(base + 256);
    unsigned short* w1df = w1sf + WBLK;
    unsigned short* w2f  = w1df + WBLK;
    unsigned short* wpf  = w2f  + WBLK;                  // 2 blocks (768 rows)
    unsigned short* snxb = wpf  + 2*(size_t)WBLK;        // 2048*384 bf16
    unsigned short* aggb = snxb + (size_t)NSUPER*HIDDEN;
    unsigned short* aggp = aggb + (size_t)NSUPER*HIDDEN; // 2048*384 bf16
    float* cntf = (float*)(aggp + (size_t)NSUPER*HIDDEN); // 2048 f32

    hipLaunchKernelGGL(prep, dim3(393), dim3(256), 0, stream,
                       W1, W2, Wp, (const unsigned int*)mask,
                       pos, feat, sn, W_in, b_in,
                       w1sf, w1df, w2f, wpf, snxb, flag);
    hipLaunchKernelGGL(k_mlp, dim3(1024), dim3(256), 0, stream,
                       pos, feat, nbr, mask, flag, W_in, b_in,
                       snxb, w1sf, w1df, b1, aggp, cntf);
    hipLaunchKernelGGL(k_agg, dim3(128), dim3(256), 0, stream,
                       aggp, w2f, b2, cntf, aggb);
    hipLaunchKernelGGL(k_proj, dim3(128), dim3(256), 0, stream,
                       aggb, snxb, wpf, bpv, out);
}